// Round 5
// baseline (615.512 us; speedup 1.0000x reference)
//
#include <hip/hip_runtime.h>
#include <stdint.h>

#define BLK 256

constexpr int Bsz = 8, Ccls = 19, Hh = 512, Ww = 1024;
constexpr int Npix = Hh * Ww;          // 2^19
constexpr int TotPix = Bsz * Npix;     // 2^22
constexpr int NGroup = Bsz * Ccls;     // 152
// 14-bit radix key: key = (u>>12) - (122<<11); mp in [1/19,1) -> exp 122..126
// -> key in [0, 5*2048) = [0,10240). Bin width ~2^-11 relative: threshold
// granularity ~40 px/group -> loss error ~5e-5 << 2.75e-2 tolerance.
constexpr int NB = 10240;              // = 256 threads * 40 bins
constexpr int KEY_BASE = 122 << 11;

__device__ __forceinline__ int key_of(uint32_t u) {
  int k = (int)(u >> 12) - KEY_BASE;
  return k < 0 ? 0 : (k > NB - 1 ? NB - 1 : k);
}

// ---------------------------------------------------------------------------
// K1: R2-style register-tile max/argmax/softmax-denom + global 14-bit hist.
// 1024 blocks: blk = b*128 + s owns px [s*4096,(s+1)*4096) of image b.
// 19 float4 loads -> full tile in regs (best-measured structure, R2).
// Atomics: 4M adds spread over ~57K live bins -> negligible contention.
// ---------------------------------------------------------------------------
__global__ __launch_bounds__(BLK) void k_fused(const float* __restrict__ pred,
                                               float4* __restrict__ mp_out,
                                               uchar4* __restrict__ lab_out,
                                               uint32_t* __restrict__ hist) {
  int t = threadIdx.x;
  int blk = blockIdx.x;
  int b = blk >> 7;
  int s = blk & 127;
  const float* ibase = pred + (size_t)b * Ccls * Npix;

  for (int j = 0; j < 4; ++j) {
    int n = s * 4096 + j * 1024 + t * 4;
    float4 v[Ccls];
#pragma unroll
    for (int c = 0; c < Ccls; ++c)
      v[c] = *(const float4*)(ibase + (size_t)c * Npix + n);

    float mp[4]; int lc[4];
#pragma unroll
    for (int q = 0; q < 4; ++q) {
      float m = ((const float*)&v[0])[q]; int l = 0;
#pragma unroll
      for (int c = 1; c < Ccls; ++c) {
        float x = ((const float*)&v[c])[q];
        if (x > m) { m = x; l = c; }       // strict > : first-max argmax
      }
      float sum = 0.f;
#pragma unroll
      for (int c = 0; c < Ccls; ++c) sum += __expf(((const float*)&v[c])[q] - m);
      mp[q] = 1.0f / sum;
      lc[q] = l;
      atomicAdd(&hist[(size_t)(b * Ccls + l) * NB + key_of(__float_as_uint(mp[q]))], 1u);
    }
    int p4 = b * (Npix / 4) + (n >> 2);
    mp_out[p4] = make_float4(mp[0], mp[1], mp[2], mp[3]);
    lab_out[p4] = make_uchar4((uint8_t)lc[0], (uint8_t)lc[1], (uint8_t)lc[2], (uint8_t)lc[3]);
  }
}

// ---------------------------------------------------------------------------
// K2: per-group descending scan over 10240 bins -> direct threshold.
// Thread t owns 40 bins descending from NB-1-t*40. mask_topk == u >= thresh.
// ---------------------------------------------------------------------------
__global__ __launch_bounds__(BLK) void k_select(const uint32_t* __restrict__ hist,
                                                uint32_t* __restrict__ thresh) {
  int g = blockIdx.x;
  int t = threadIdx.x;
  const uint32_t* h = hist + (size_t)g * NB;
  uint32_t loc[40]; uint32_t psum = 0;
  int hi = NB - 1 - t * 40;
#pragma unroll
  for (int i = 0; i < 40; ++i) { loc[i] = h[hi - i]; psum += loc[i]; }
  __shared__ uint32_t sc[BLK];
  sc[t] = psum;
  __syncthreads();
  for (int ofs = 1; ofs < BLK; ofs <<= 1) {
    uint32_t vv = (t >= ofs) ? sc[t - ofs] : 0u;
    __syncthreads();
    sc[t] += vv;
    __syncthreads();
  }
  uint32_t incl = sc[t];
  uint32_t excl = incl - psum;
  uint32_t total = sc[BLK - 1];
  int k = (int)((float)total * 0.66f);   // matches jnp f32 mul + trunc
  if (t == 0 && k == 0) thresh[g] = 0x7F800000u;  // select none via topk
  if (k > 0 && (int)excl < k && k <= (int)incl) {
    uint32_t cum = excl;
#pragma unroll
    for (int i = 0; i < 40; ++i) {
      if ((uint32_t)k <= cum + loc[i]) {
        thresh[g] = (uint32_t)(hi - i + KEY_BASE) << 12;  // low edge of bin
        break;
      }
      cum += loc[i];
    }
  }
}

// ---------------------------------------------------------------------------
// K3: masked reduction + last-block finalize. nll(pseudo) == -log(max_prob).
// ---------------------------------------------------------------------------
__global__ __launch_bounds__(BLK) void k_loss(const float4* __restrict__ mp_arr,
                                              const uchar4* __restrict__ lab,
                                              const uint32_t* __restrict__ thresh,
                                              float* __restrict__ gsum,
                                              uint32_t* __restrict__ gcnt,
                                              uint32_t* __restrict__ ticket,
                                              float* __restrict__ out) {
  int p4 = blockIdx.x * BLK + threadIdx.x;
  int b = p4 >> 17;                      // / (Npix/4)
  float4 m = mp_arr[p4];
  uchar4 l = lab[p4];
  const float* mf = (const float*)&m;
  const uint8_t* lf = (const uint8_t*)&l;
  float vs = 0.f; uint32_t vc = 0u;
#pragma unroll
  for (int q = 0; q < 4; ++q) {
    float mp = mf[q];
    int g = b * Ccls + (int)lf[q];
    uint32_t u = __float_as_uint(mp);
    bool sel = (mp > 0.9f) || (u >= thresh[g]);
    if (sel) { vs += -logf(mp); vc += 1u; }
  }
#pragma unroll
  for (int o = 32; o > 0; o >>= 1) {
    vs += __shfl_down(vs, o, 64);
    vc += __shfl_down(vc, o, 64);
  }
  __shared__ float ssum[BLK / 64];
  __shared__ uint32_t scnt[BLK / 64];
  int wave = threadIdx.x >> 6;
  int lane = threadIdx.x & 63;
  if (lane == 0) { ssum[wave] = vs; scnt[wave] = vc; }
  __syncthreads();
  if (threadIdx.x == 0) {
    float ts = 0.f; uint32_t tc = 0u;
#pragma unroll
    for (int w = 0; w < BLK / 64; ++w) { ts += ssum[w]; tc += scnt[w]; }
    atomicAdd(gsum, ts);
    atomicAdd(gcnt, tc);
    __threadfence();
    uint32_t done = atomicAdd(ticket, 1u);
    if (done == gridDim.x - 1) {
      float fs = atomicAdd(gsum, 0.0f);     // coherent read-back
      uint32_t fc = atomicAdd(gcnt, 0u);
      out[0] = fs / (float)(fc > 0u ? fc : 1u);
    }
  }
}

// ---------------------------------------------------------------------------
extern "C" void kernel_launch(void* const* d_in, const int* in_sizes, int n_in,
                              void* d_out, int out_size, void* d_ws, size_t ws_size,
                              hipStream_t stream) {
  const float* pred = (const float*)d_in[0];
  char* ws = (char*)d_ws;
  size_t off = 0;
  auto carve = [&](size_t bytes) -> void* {
    void* p = ws + off;
    off = (off + bytes + 255) & ~(size_t)255;
    return p;
  };
  float*    mp    = (float*)carve((size_t)TotPix * 4);
  uint8_t*  lab   = (uint8_t*)carve((size_t)TotPix);
  uint32_t* thr   = (uint32_t*)carve((size_t)NGroup * 4);   // fully written by k_select
  size_t zero_off = off;                 // memset region: hist + gsum + gcnt + ticket
  uint32_t* hist  = (uint32_t*)carve((size_t)NGroup * NB * 4);  // 6.2 MB
  float*    gsum  = (float*)carve(4);
  uint32_t* gcnt  = (uint32_t*)carve(4);
  uint32_t* tick  = (uint32_t*)carve(4);

  hipMemsetAsync(ws + zero_off, 0, off - zero_off, stream);

  int nblk4 = TotPix / (BLK * 4);        // 4096
  k_fused <<<Bsz * 128, BLK, 0, stream>>>(pred, (float4*)mp, (uchar4*)lab, hist);
  k_select<<<NGroup,    BLK, 0, stream>>>(hist, thr);
  k_loss  <<<nblk4,     BLK, 0, stream>>>((const float4*)mp, (const uchar4*)lab, thr,
                                          gsum, gcnt, tick, (float*)d_out);
}